// Round 6
// baseline (169.606 us; speedup 1.0000x reference)
//
#include <hip/hip_runtime.h>

#define B 4
#define N 2048      // N1 == N2
#define F 256
#define O 256
#define LOG2E 1.4426950408889634f
#define NEG_BIG -9000000000000000.0f

typedef _Float16 f16;
typedef f16 f16x8 __attribute__((ext_vector_type(8)));
typedef float f32x16 __attribute__((ext_vector_type(16)));

// ws float-index layout (small scalars region)
#define WS_V1 0
#define WS_V2 256
#define WS_T1 512              // t1 * LOG2E  per (b,n2)
#define WS_T2 (512 + B*N)     // t2 (unscaled) per (b,n2)
// byte offsets in d_ws
#define WT_OFF (1u << 20)     // wordT swizzled: f16 [B][ft(8)][kc(128)][lane(64)][8] (4 MB)
#define W_OFF  (8u << 20)     // W: f16 [B*N][N] softmax weights row-major (33.5 MB)

__device__ __forceinline__ float alpha_of(float pre2) {
  return __builtin_amdgcn_exp2f(fmaxf(pre2, 0.2f * pre2));
}

// ---------------- kernel 1: v1 = W1 @ w3a, v2 = W2 @ w3b ----------------
__global__ __launch_bounds__(256) void k_v(const float* __restrict__ W1,
                                           const float* __restrict__ W2,
                                           const float* __restrict__ w3,
                                           float* __restrict__ ws) {
  int tid = threadIdx.x;
  int lane = tid & 63;
  int f = blockIdx.x * 4 + (tid >> 6);
  float a = 0.f, b = 0.f;
  #pragma unroll
  for (int k = 0; k < 4; ++k) {
    int o = lane + 64 * k;
    a += W1[f * O + o] * w3[o];
    b += W2[f * O + o] * w3[O + o];
  }
  #pragma unroll
  for (int off = 32; off > 0; off >>= 1) {
    a += __shfl_down(a, off);
    b += __shfl_down(b, off);
  }
  if (lane == 0) {
    ws[WS_V1 + f] = a;
    ws[WS_V2 + f] = b;
  }
}

// ---------------- kernel 2: k_prep = t1/t2 dots + swizzled f16 transpose ----
__global__ __launch_bounds__(256) void k_prep(const float* __restrict__ word,
                                              float* __restrict__ ws,
                                              f16* __restrict__ wordT) {
  __shared__ float v1s[F], v2s[F];
  __shared__ __align__(16) f16 tile[F][40];   // [f][r]
  int t = threadIdx.x;
  int k0 = blockIdx.x * 32;
  int b = blockIdx.y;

  if (t < 64)       ((float4*)v1s)[t]      = ((const float4*)(ws + WS_V1))[t];
  else if (t < 128) ((float4*)v2s)[t - 64] = ((const float4*)(ws + WS_V2))[t - 64];
  __syncthreads();

  int r = t >> 3;        // 0..31
  int cg = t & 7;
  const float* wrow = word + ((size_t)(b * N + k0 + r)) * F;
  float a = 0.f, bb = 0.f;
  #pragma unroll
  for (int i = 0; i < 8; ++i) {
    int c = i * 32 + cg * 4;
    float4 w = *(const float4*)(wrow + c);
    float4 x1 = *(const float4*)(v1s + c);
    float4 x2 = *(const float4*)(v2s + c);
    a  += w.x * x1.x + w.y * x1.y + w.z * x1.z + w.w * x1.w;
    bb += w.x * x2.x + w.y * x2.y + w.z * x2.z + w.w * x2.w;
    tile[c + 0][r] = (f16)w.x;
    tile[c + 1][r] = (f16)w.y;
    tile[c + 2][r] = (f16)w.z;
    tile[c + 3][r] = (f16)w.w;
  }
  #pragma unroll
  for (int off = 4; off > 0; off >>= 1) {
    a  += __shfl_down(a, off);
    bb += __shfl_down(bb, off);
  }
  if (cg == 0) {
    ws[WS_T1 + b * N + k0 + r] = a * LOG2E;
    ws[WS_T2 + b * N + k0 + r] = bb;
  }
  __syncthreads();

  // swizzled writes: [ft][kc][lane][8]; B-frag: f = ft*32+(l&31), k = kc*16+(l>>5)*8+j
  size_t base = (size_t)b * F * N;
  #pragma unroll
  for (int i = 0; i < 4; ++i) {
    int idx = t + 256 * i;
    int ft = idx >> 7, c = (idx >> 6) & 1, l = idx & 63;
    int f = ft * 32 + (l & 31);
    int rr = c * 16 + ((l >> 5) * 8);
    f16x8 h = *(const f16x8*)&tile[f][rr];
    *(f16x8*)(wordT + base + ((size_t)((ft * 128 + (k0 >> 4) + c) * 64 + l)) * 8) = h;
  }
}

// -------- kernel 3: per-row stats + fused softmax-weight write (f16) --------
// one block per (b,n1) adj row; writes W[row][0..N) f16 row-major.
__global__ __launch_bounds__(256) void k_stats(const float* __restrict__ adj,
                                               float* __restrict__ ws,
                                               f16* __restrict__ Wm) {
  int row = blockIdx.x;
  int b = row >> 11;
  int t = threadIdx.x;
  int wid = t >> 6, lane = t & 63;
  const float* arow = adj + (size_t)row * N;
  const float* t1b = ws + WS_T1 + b * N;
  const float* t2b = ws + WS_T2 + b * N;

  float4 a0 = *(const float4*)(arow + t * 8);
  float4 a1 = *(const float4*)(arow + t * 8 + 4);
  float4 u0 = *(const float4*)(t2b + t * 8);
  float4 u1 = *(const float4*)(t2b + t * 8 + 4);
  float deg = a0.x + a0.y + a0.z + a0.w + a1.x + a1.y + a1.z + a1.w;
  float dot = a0.x * u0.x + a0.y * u0.y + a0.z * u0.z + a0.w * u0.w +
              a1.x * u1.x + a1.y * u1.y + a1.z * u1.z + a1.w * u1.w;
  unsigned mb = (a0.x > 0.f ? 1u : 0u) | (a0.y > 0.f ? 2u : 0u) |
                (a0.z > 0.f ? 4u : 0u) | (a0.w > 0.f ? 8u : 0u) |
                (a1.x > 0.f ? 16u : 0u) | (a1.y > 0.f ? 32u : 0u) |
                (a1.z > 0.f ? 64u : 0u) | (a1.w > 0.f ? 128u : 0u);

  #pragma unroll
  for (int off = 32; off > 0; off >>= 1) {
    deg += __shfl_down(deg, off);
    dot += __shfl_down(dot, off);
  }
  __shared__ float rd[4], rt[4], rm[4], rz[4];
  if (lane == 0) { rd[wid] = deg; rt[wid] = dot; }
  __syncthreads();
  deg = rd[0] + rd[1] + rd[2] + rd[3];
  dot = rt[0] + rt[1] + rt[2] + rt[3];
  float degc = deg > 0.f ? deg : 1.f;
  float s2p = (dot / degc) * LOG2E;

  float4 p0 = *(const float4*)(t1b + t * 8);
  float4 p1 = *(const float4*)(t1b + t * 8 + 4);
  float al[8];
  al[0] = (mb & 1)   ? alpha_of(p0.x + s2p) : NEG_BIG;
  al[1] = (mb & 2)   ? alpha_of(p0.y + s2p) : NEG_BIG;
  al[2] = (mb & 4)   ? alpha_of(p0.z + s2p) : NEG_BIG;
  al[3] = (mb & 8)   ? alpha_of(p0.w + s2p) : NEG_BIG;
  al[4] = (mb & 16)  ? alpha_of(p1.x + s2p) : NEG_BIG;
  al[5] = (mb & 32)  ? alpha_of(p1.y + s2p) : NEG_BIG;
  al[6] = (mb & 64)  ? alpha_of(p1.z + s2p) : NEG_BIG;
  al[7] = (mb & 128) ? alpha_of(p1.w + s2p) : NEG_BIG;
  float m = NEG_BIG;
  #pragma unroll
  for (int j = 0; j < 8; ++j) m = fmaxf(m, al[j]);
  #pragma unroll
  for (int off = 32; off > 0; off >>= 1) m = fmaxf(m, __shfl_down(m, off));
  if (lane == 0) rm[wid] = m;
  __syncthreads();
  m = fmaxf(fmaxf(rm[0], rm[1]), fmaxf(rm[2], rm[3]));

  float negmL = -m * LOG2E;
  float z = 0.f;
  #pragma unroll
  for (int j = 0; j < 8; ++j) z += __builtin_amdgcn_exp2f(fmaf(al[j], LOG2E, negmL));
  #pragma unroll
  for (int off = 32; off > 0; off >>= 1) z += __shfl_down(z, off);
  if (lane == 0) rz[wid] = z;
  __syncthreads();
  float zf = rz[0] + rz[1] + rz[2] + rz[3];

  // finalize weights: w = exp(al - m)/Z for edges, 0 for non-edges, 1/N if deg==0
  float cr, wn;
  if (deg > 0.f) { cr = negmL - log2f(zf); wn = 0.f; }
  else           { cr = 0.f;               wn = 1.0f / (float)N; }
  f16x8 hw;
  #pragma unroll
  for (int j = 0; j < 8; ++j) {
    float w = ((mb >> j) & 1u) ? __builtin_amdgcn_exp2f(fmaf(al[j], LOG2E, cr)) : wn;
    hw[j] = (f16)w;
  }
  *(f16x8*)(Wm + (size_t)row * N + t * 8) = hw;
}

// ---------------- kernel 4: pure f16 MFMA GEMM (no LDS, no barriers) --------
// out[8192,256] = W[8192,2048] @ word[2048,256].
// grid 512 blocks x 128 thr (2 waves). Block: fg = bid&3 (64-col group),
// mp = bid>>2; wave w handles 32-row tile mblk = mp*2+w. Both waves share the
// same two B panels -> L1 reuse. A direct from W row-major (lane = row frag),
// B direct from frag-swizzled wordT (lane-contiguous 16B).
__global__ __launch_bounds__(128) void k_gemm(const f16* __restrict__ Wm,
                                              const f16* __restrict__ wordT,
                                              float* __restrict__ out) {
  const int t = threadIdx.x;
  const int l = t & 63;
  const int w = t >> 6;                  // 0..1
  const int fg = blockIdx.x & 3;
  const int mp = blockIdx.x >> 2;        // 0..127
  const int m0 = (mp * 2 + w) * 32;
  const int b = m0 >> 11;
  const int f0 = fg * 64;

  // A-frag: lane l -> row m0+(l&31), k = kc*16 + (l>>5)*8 + j
  const f16* Ap = Wm + (size_t)(m0 + (l & 31)) * N + (l >> 5) * 8;
  // B-frag: panel ft = fg*2 (+1): [ft][kc][lane][8]
  const f16* Bp = wordT + (size_t)b * F * N + ((size_t)(fg * 2) * 128 * 64 + l) * 8;

  f32x16 acc0 = {0.f,0.f,0.f,0.f,0.f,0.f,0.f,0.f,0.f,0.f,0.f,0.f,0.f,0.f,0.f,0.f};
  f32x16 acc1 = {0.f,0.f,0.f,0.f,0.f,0.f,0.f,0.f,0.f,0.f,0.f,0.f,0.f,0.f,0.f,0.f};

  for (int kc = 0; kc < 128; kc += 8) {
    f16x8 a[8], p[8], q[8];
    #pragma unroll
    for (int c = 0; c < 8; ++c) {
      a[c] = *(const f16x8*)(Ap + (size_t)(kc + c) * 16);
      p[c] = *(const f16x8*)(Bp + (size_t)(kc + c) * 512);
      q[c] = *(const f16x8*)(Bp + 65536 + (size_t)(kc + c) * 512);
    }
    #pragma unroll
    for (int c = 0; c < 8; ++c) {
      acc0 = __builtin_amdgcn_mfma_f32_32x32x16_f16(a[c], p[c], acc0, 0, 0, 0);
      acc1 = __builtin_amdgcn_mfma_f32_32x32x16_f16(a[c], q[c], acc1, 0, 0, 0);
    }
  }

  // C layout (m74/m101): col = lane&31, row = (reg&3)+8*(reg>>2)+4*(lane>>5)
  #pragma unroll
  for (int reg = 0; reg < 16; ++reg) {
    int row = m0 + (reg & 3) + 8 * (reg >> 2) + 4 * (l >> 5);
    out[(size_t)row * F + f0 + (l & 31)]      = acc0[reg];
    out[(size_t)row * F + f0 + 32 + (l & 31)] = acc1[reg];
  }
}

extern "C" void kernel_launch(void* const* d_in, const int* in_sizes, int n_in,
                              void* d_out, int out_size, void* d_ws, size_t ws_size,
                              hipStream_t stream) {
  const float* word = (const float*)d_in[0];
  const float* adj  = (const float*)d_in[1];
  const float* W1   = (const float*)d_in[2];
  const float* W2   = (const float*)d_in[3];
  const float* w3   = (const float*)d_in[4];
  float* out = (float*)d_out;
  float* ws  = (float*)d_ws;
  f16* wordT = (f16*)((char*)d_ws + WT_OFF);
  f16* Wm    = (f16*)((char*)d_ws + W_OFF);

  k_v<<<64, 256, 0, stream>>>(W1, W2, w3, ws);
  k_prep<<<dim3(N / 32, B), 256, 0, stream>>>(word, ws, wordT);
  k_stats<<<B * N, 256, 0, stream>>>(adj, ws, Wm);
  k_gemm<<<512, 128, 0, stream>>>(Wm, wordT, out);
}

// Round 7
// 158.395 us; speedup vs baseline: 1.0708x; 1.0708x over previous
//
#include <hip/hip_runtime.h>

#define B 4
#define N 2048      // N1 == N2
#define F 256
#define O 256
#define LOG2E 1.4426950408889634f
#define NEG_BIG -9000000000000000.0f

typedef _Float16 f16;
typedef f16 f16x8 __attribute__((ext_vector_type(8)));
typedef float f32x16 __attribute__((ext_vector_type(16)));

// ws float-index layout (small scalars region)
#define WS_V1 0
#define WS_V2 256
#define WS_T1 512              // t1 * LOG2E  per (b,n2)
#define WS_T2 (512 + B*N)     // t2 (unscaled) per (b,n2)
// byte offsets in d_ws
#define WT_OFF (1u << 20)     // wordT swizzled: f16 [B][ft(8)][kc(128)][lane(64)][8] (4 MB)
#define W_OFF  (8u << 20)     // W: f16 [B*N][N] softmax weights row-major (33.5 MB)

__device__ __forceinline__ float alpha_of(float pre2) {
  return __builtin_amdgcn_exp2f(fmaxf(pre2, 0.2f * pre2));
}

// ---------------- kernel 1: v1 = W1 @ w3a, v2 = W2 @ w3b ----------------
__global__ __launch_bounds__(256) void k_v(const float* __restrict__ W1,
                                           const float* __restrict__ W2,
                                           const float* __restrict__ w3,
                                           float* __restrict__ ws) {
  int tid = threadIdx.x;
  int lane = tid & 63;
  int f = blockIdx.x * 4 + (tid >> 6);
  float a = 0.f, b = 0.f;
  #pragma unroll
  for (int k = 0; k < 4; ++k) {
    int o = lane + 64 * k;
    a += W1[f * O + o] * w3[o];
    b += W2[f * O + o] * w3[O + o];
  }
  #pragma unroll
  for (int off = 32; off > 0; off >>= 1) {
    a += __shfl_down(a, off);
    b += __shfl_down(b, off);
  }
  if (lane == 0) {
    ws[WS_V1 + f] = a;
    ws[WS_V2 + f] = b;
  }
}

// ---------------- kernel 2: k_prep = t1/t2 dots + swizzled f16 transpose ----
__global__ __launch_bounds__(256) void k_prep(const float* __restrict__ word,
                                              float* __restrict__ ws,
                                              f16* __restrict__ wordT) {
  __shared__ float v1s[F], v2s[F];
  __shared__ __align__(16) f16 tile[F][40];   // [f][r]
  int t = threadIdx.x;
  int k0 = blockIdx.x * 32;
  int b = blockIdx.y;

  if (t < 64)       ((float4*)v1s)[t]      = ((const float4*)(ws + WS_V1))[t];
  else if (t < 128) ((float4*)v2s)[t - 64] = ((const float4*)(ws + WS_V2))[t - 64];
  __syncthreads();

  int r = t >> 3;        // 0..31
  int cg = t & 7;
  const float* wrow = word + ((size_t)(b * N + k0 + r)) * F;
  float a = 0.f, bb = 0.f;
  #pragma unroll
  for (int i = 0; i < 8; ++i) {
    int c = i * 32 + cg * 4;
    float4 w = *(const float4*)(wrow + c);
    float4 x1 = *(const float4*)(v1s + c);
    float4 x2 = *(const float4*)(v2s + c);
    a  += w.x * x1.x + w.y * x1.y + w.z * x1.z + w.w * x1.w;
    bb += w.x * x2.x + w.y * x2.y + w.z * x2.z + w.w * x2.w;
    tile[c + 0][r] = (f16)w.x;
    tile[c + 1][r] = (f16)w.y;
    tile[c + 2][r] = (f16)w.z;
    tile[c + 3][r] = (f16)w.w;
  }
  #pragma unroll
  for (int off = 4; off > 0; off >>= 1) {
    a  += __shfl_down(a, off);
    bb += __shfl_down(bb, off);
  }
  if (cg == 0) {
    ws[WS_T1 + b * N + k0 + r] = a * LOG2E;
    ws[WS_T2 + b * N + k0 + r] = bb;
  }
  __syncthreads();

  // swizzled writes: [ft][kc][lane][8]; B-frag: f = ft*32+(l&31), k = kc*16+(l>>5)*8+j
  size_t base = (size_t)b * F * N;
  #pragma unroll
  for (int i = 0; i < 4; ++i) {
    int idx = t + 256 * i;
    int ft = idx >> 7, c = (idx >> 6) & 1, l = idx & 63;
    int f = ft * 32 + (l & 31);
    int rr = c * 16 + ((l >> 5) * 8);
    f16x8 h = *(const f16x8*)&tile[f][rr];
    *(f16x8*)(wordT + base + ((size_t)((ft * 128 + (k0 >> 4) + c) * 64 + l)) * 8) = h;
  }
}

// -------- kernel 3: per-row stats + fused softmax-weight write (f16) --------
__global__ __launch_bounds__(256) void k_stats(const float* __restrict__ adj,
                                               float* __restrict__ ws,
                                               f16* __restrict__ Wm) {
  int row = blockIdx.x;
  int b = row >> 11;
  int t = threadIdx.x;
  int wid = t >> 6, lane = t & 63;
  const float* arow = adj + (size_t)row * N;
  const float* t1b = ws + WS_T1 + b * N;
  const float* t2b = ws + WS_T2 + b * N;

  float4 a0 = *(const float4*)(arow + t * 8);
  float4 a1 = *(const float4*)(arow + t * 8 + 4);
  float4 u0 = *(const float4*)(t2b + t * 8);
  float4 u1 = *(const float4*)(t2b + t * 8 + 4);
  float deg = a0.x + a0.y + a0.z + a0.w + a1.x + a1.y + a1.z + a1.w;
  float dot = a0.x * u0.x + a0.y * u0.y + a0.z * u0.z + a0.w * u0.w +
              a1.x * u1.x + a1.y * u1.y + a1.z * u1.z + a1.w * u1.w;
  unsigned mb = (a0.x > 0.f ? 1u : 0u) | (a0.y > 0.f ? 2u : 0u) |
                (a0.z > 0.f ? 4u : 0u) | (a0.w > 0.f ? 8u : 0u) |
                (a1.x > 0.f ? 16u : 0u) | (a1.y > 0.f ? 32u : 0u) |
                (a1.z > 0.f ? 64u : 0u) | (a1.w > 0.f ? 128u : 0u);

  #pragma unroll
  for (int off = 32; off > 0; off >>= 1) {
    deg += __shfl_down(deg, off);
    dot += __shfl_down(dot, off);
  }
  __shared__ float rd[4], rt[4], rm[4], rz[4];
  if (lane == 0) { rd[wid] = deg; rt[wid] = dot; }
  __syncthreads();
  deg = rd[0] + rd[1] + rd[2] + rd[3];
  dot = rt[0] + rt[1] + rt[2] + rt[3];
  float degc = deg > 0.f ? deg : 1.f;
  float s2p = (dot / degc) * LOG2E;

  float4 p0 = *(const float4*)(t1b + t * 8);
  float4 p1 = *(const float4*)(t1b + t * 8 + 4);
  float al[8];
  al[0] = (mb & 1)   ? alpha_of(p0.x + s2p) : NEG_BIG;
  al[1] = (mb & 2)   ? alpha_of(p0.y + s2p) : NEG_BIG;
  al[2] = (mb & 4)   ? alpha_of(p0.z + s2p) : NEG_BIG;
  al[3] = (mb & 8)   ? alpha_of(p0.w + s2p) : NEG_BIG;
  al[4] = (mb & 16)  ? alpha_of(p1.x + s2p) : NEG_BIG;
  al[5] = (mb & 32)  ? alpha_of(p1.y + s2p) : NEG_BIG;
  al[6] = (mb & 64)  ? alpha_of(p1.z + s2p) : NEG_BIG;
  al[7] = (mb & 128) ? alpha_of(p1.w + s2p) : NEG_BIG;
  float m = NEG_BIG;
  #pragma unroll
  for (int j = 0; j < 8; ++j) m = fmaxf(m, al[j]);
  #pragma unroll
  for (int off = 32; off > 0; off >>= 1) m = fmaxf(m, __shfl_down(m, off));
  if (lane == 0) rm[wid] = m;
  __syncthreads();
  m = fmaxf(fmaxf(rm[0], rm[1]), fmaxf(rm[2], rm[3]));

  float negmL = -m * LOG2E;
  float z = 0.f;
  #pragma unroll
  for (int j = 0; j < 8; ++j) z += __builtin_amdgcn_exp2f(fmaf(al[j], LOG2E, negmL));
  #pragma unroll
  for (int off = 32; off > 0; off >>= 1) z += __shfl_down(z, off);
  if (lane == 0) rz[wid] = z;
  __syncthreads();
  float zf = rz[0] + rz[1] + rz[2] + rz[3];

  float cr, wn;
  if (deg > 0.f) { cr = negmL - log2f(zf); wn = 0.f; }
  else           { cr = 0.f;               wn = 1.0f / (float)N; }
  f16x8 hw;
  #pragma unroll
  for (int j = 0; j < 8; ++j) {
    float w = ((mb >> j) & 1u) ? __builtin_amdgcn_exp2f(fmaf(al[j], LOG2E, cr)) : wn;
    hw[j] = (f16)w;
  }
  *(f16x8*)(Wm + (size_t)row * N + t * 8) = hw;
}

// ---------------- kernel 4: f16 MFMA GEMM, K-split 2, high occupancy --------
// out[8192,256] = W[8192,2048] @ word[2048,256].
// grid 1024 (rt*4+fg), 256 thr = 4 waves: wave w -> fsub = w&1, ks = w>>1.
// Wave tile: 32 rows x 32 cols, K-half = 1024 (64 chunks). 16 waves/CU.
// Register ping-pong: next 4-chunk batch loads issued before current MFMAs.
// Single barrier: ks=1 waves dump acc to LDS, ks=0 add + store.
__global__ __launch_bounds__(256, 4) void k_gemm(const f16* __restrict__ Wm,
                                                 const f16* __restrict__ wordT,
                                                 float* __restrict__ out) {
  __shared__ float red[2][16][64];   // 8KB

  const int t = threadIdx.x;
  const int l = t & 63;
  const int w = t >> 6;
  const int fsub = w & 1;
  const int ks = w >> 1;
  const int rt = blockIdx.x >> 2;
  const int fg = blockIdx.x & 3;
  const int m0 = rt * 32;
  const int b = m0 >> 11;
  const int ft = fg * 2 + fsub;

  // A-frag: lane l -> row m0+(l&31), k = ks*1024 + kc*16 + (l>>5)*8 + j
  const f16* Ap = Wm + (size_t)(m0 + (l & 31)) * N + ks * 1024 + (l >> 5) * 8;
  // B-frag: [ft][kcglob][lane][8], kcglob = ks*64 + kc
  const f16* Bp = wordT + (size_t)b * F * N + ((size_t)(ft * 128 + ks * 64) * 64 + l) * 8;

  f32x16 acc = {0.f,0.f,0.f,0.f,0.f,0.f,0.f,0.f,0.f,0.f,0.f,0.f,0.f,0.f,0.f,0.f};

  f16x8 a0[4], b0[4], a1[4], b1[4];
  #pragma unroll
  for (int c = 0; c < 4; ++c) {
    a0[c] = *(const f16x8*)(Ap + (size_t)c * 16);
    b0[c] = *(const f16x8*)(Bp + (size_t)c * 512);
  }

  for (int kc = 0; kc < 64; kc += 8) {
    #pragma unroll
    for (int c = 0; c < 4; ++c) {
      a1[c] = *(const f16x8*)(Ap + (size_t)(kc + 4 + c) * 16);
      b1[c] = *(const f16x8*)(Bp + (size_t)(kc + 4 + c) * 512);
    }
    #pragma unroll
    for (int c = 0; c < 4; ++c)
      acc = __builtin_amdgcn_mfma_f32_32x32x16_f16(a0[c], b0[c], acc, 0, 0, 0);
    if (kc + 8 < 64) {
      #pragma unroll
      for (int c = 0; c < 4; ++c) {
        a0[c] = *(const f16x8*)(Ap + (size_t)(kc + 8 + c) * 16);
        b0[c] = *(const f16x8*)(Bp + (size_t)(kc + 8 + c) * 512);
      }
    }
    #pragma unroll
    for (int c = 0; c < 4; ++c)
      acc = __builtin_amdgcn_mfma_f32_32x32x16_f16(a1[c], b1[c], acc, 0, 0, 0);
  }

  // cross-wave K reduction
  if (ks == 1) {
    #pragma unroll
    for (int reg = 0; reg < 16; ++reg) red[fsub][reg][l] = acc[reg];
  }
  __syncthreads();
  if (ks == 0) {
    const int fcol = ft * 32 + (l & 31);
    #pragma unroll
    for (int reg = 0; reg < 16; ++reg) {
      float v = acc[reg] + red[fsub][reg][l];
      int row = m0 + (reg & 3) + 8 * (reg >> 2) + 4 * (l >> 5);
      out[(size_t)row * F + fcol] = v;
    }
  }
}

extern "C" void kernel_launch(void* const* d_in, const int* in_sizes, int n_in,
                              void* d_out, int out_size, void* d_ws, size_t ws_size,
                              hipStream_t stream) {
  const float* word = (const float*)d_in[0];
  const float* adj  = (const float*)d_in[1];
  const float* W1   = (const float*)d_in[2];
  const float* W2   = (const float*)d_in[3];
  const float* w3   = (const float*)d_in[4];
  float* out = (float*)d_out;
  float* ws  = (float*)d_ws;
  f16* wordT = (f16*)((char*)d_ws + WT_OFF);
  f16* Wm    = (f16*)((char*)d_ws + W_OFF);

  k_v<<<64, 256, 0, stream>>>(W1, W2, w3, ws);
  k_prep<<<dim3(N / 32, B), 256, 0, stream>>>(word, ws, wordT);
  k_stats<<<B * N, 256, 0, stream>>>(adj, ws, Wm);
  k_gemm<<<1024, 256, 0, stream>>>(Wm, wordT, out);
}

// Round 9
// 158.128 us; speedup vs baseline: 1.0726x; 1.0017x over previous
//
#include <hip/hip_runtime.h>

#define B 4
#define N 2048      // N1 == N2
#define F 256
#define O 256
#define LOG2E 1.4426950408889634f
#define NEG_BIG -9000000000000000.0f

typedef _Float16 f16;
typedef f16 f16x8 __attribute__((ext_vector_type(8)));
typedef float f32x16 __attribute__((ext_vector_type(16)));

// ws float-index layout (small scalars region)
#define WS_V1 0
#define WS_V2 256
#define WS_T1 512              // t1 * LOG2E  per (b,n2)
#define WS_T2 (512 + B*N)     // t2 (unscaled) per (b,n2)
// byte offsets in d_ws
#define WT_OFF (1u << 20)     // wordT swizzled: f16 [B][ft(8)][kc(128)][lane(64)][8] (4 MB)
#define W_OFF  (8u << 20)     // W: f16 [B*N][N] softmax weights row-major (33.5 MB)

__device__ __forceinline__ float alpha_of(float pre2) {
  return __builtin_amdgcn_exp2f(fmaxf(pre2, 0.2f * pre2));
}

// ---------------- kernel 1: v1 = W1 @ w3a, v2 = W2 @ w3b ----------------
__global__ __launch_bounds__(256) void k_v(const float* __restrict__ W1,
                                           const float* __restrict__ W2,
                                           const float* __restrict__ w3,
                                           float* __restrict__ ws) {
  int tid = threadIdx.x;
  int lane = tid & 63;
  int f = blockIdx.x * 4 + (tid >> 6);
  float a = 0.f, b = 0.f;
  #pragma unroll
  for (int k = 0; k < 4; ++k) {
    int o = lane + 64 * k;
    a += W1[f * O + o] * w3[o];
    b += W2[f * O + o] * w3[O + o];
  }
  #pragma unroll
  for (int off = 32; off > 0; off >>= 1) {
    a += __shfl_down(a, off);
    b += __shfl_down(b, off);
  }
  if (lane == 0) {
    ws[WS_V1 + f] = a;
    ws[WS_V2 + f] = b;
  }
}

// ---------------- kernel 2: k_prep = t1/t2 dots + swizzled f16 transpose ----
__global__ __launch_bounds__(256) void k_prep(const float* __restrict__ word,
                                              float* __restrict__ ws,
                                              f16* __restrict__ wordT) {
  __shared__ float v1s[F], v2s[F];
  __shared__ __align__(16) f16 tile[F][40];   // [f][r]
  int t = threadIdx.x;
  int k0 = blockIdx.x * 32;
  int b = blockIdx.y;

  if (t < 64)       ((float4*)v1s)[t]      = ((const float4*)(ws + WS_V1))[t];
  else if (t < 128) ((float4*)v2s)[t - 64] = ((const float4*)(ws + WS_V2))[t - 64];
  __syncthreads();

  int r = t >> 3;        // 0..31
  int cg = t & 7;
  const float* wrow = word + ((size_t)(b * N + k0 + r)) * F;
  float a = 0.f, bb = 0.f;
  #pragma unroll
  for (int i = 0; i < 8; ++i) {
    int c = i * 32 + cg * 4;
    float4 w = *(const float4*)(wrow + c);
    float4 x1 = *(const float4*)(v1s + c);
    float4 x2 = *(const float4*)(v2s + c);
    a  += w.x * x1.x + w.y * x1.y + w.z * x1.z + w.w * x1.w;
    bb += w.x * x2.x + w.y * x2.y + w.z * x2.z + w.w * x2.w;
    tile[c + 0][r] = (f16)w.x;
    tile[c + 1][r] = (f16)w.y;
    tile[c + 2][r] = (f16)w.z;
    tile[c + 3][r] = (f16)w.w;
  }
  #pragma unroll
  for (int off = 4; off > 0; off >>= 1) {
    a  += __shfl_down(a, off);
    bb += __shfl_down(bb, off);
  }
  if (cg == 0) {
    ws[WS_T1 + b * N + k0 + r] = a * LOG2E;
    ws[WS_T2 + b * N + k0 + r] = bb;
  }
  __syncthreads();

  // swizzled writes: [ft][kc][lane][8]; B-frag: f = ft*32+(l&31), k = kc*16+(l>>5)*8+j
  size_t base = (size_t)b * F * N;
  #pragma unroll
  for (int i = 0; i < 4; ++i) {
    int idx = t + 256 * i;
    int ft = idx >> 7, c = (idx >> 6) & 1, l = idx & 63;
    int f = ft * 32 + (l & 31);
    int rr = c * 16 + ((l >> 5) * 8);
    f16x8 h = *(const f16x8*)&tile[f][rr];
    *(f16x8*)(wordT + base + ((size_t)((ft * 128 + (k0 >> 4) + c) * 64 + l)) * 8) = h;
  }
}

// -------- kernel 3: per-row stats + fused softmax-weight write (f16) --------
__global__ __launch_bounds__(256) void k_stats(const float* __restrict__ adj,
                                               float* __restrict__ ws,
                                               f16* __restrict__ Wm) {
  int row = blockIdx.x;
  int b = row >> 11;
  int t = threadIdx.x;
  int wid = t >> 6, lane = t & 63;
  const float* arow = adj + (size_t)row * N;
  const float* t1b = ws + WS_T1 + b * N;
  const float* t2b = ws + WS_T2 + b * N;

  float4 a0 = *(const float4*)(arow + t * 8);
  float4 a1 = *(const float4*)(arow + t * 8 + 4);
  float4 u0 = *(const float4*)(t2b + t * 8);
  float4 u1 = *(const float4*)(t2b + t * 8 + 4);
  float deg = a0.x + a0.y + a0.z + a0.w + a1.x + a1.y + a1.z + a1.w;
  float dot = a0.x * u0.x + a0.y * u0.y + a0.z * u0.z + a0.w * u0.w +
              a1.x * u1.x + a1.y * u1.y + a1.z * u1.z + a1.w * u1.w;
  unsigned mb = (a0.x > 0.f ? 1u : 0u) | (a0.y > 0.f ? 2u : 0u) |
                (a0.z > 0.f ? 4u : 0u) | (a0.w > 0.f ? 8u : 0u) |
                (a1.x > 0.f ? 16u : 0u) | (a1.y > 0.f ? 32u : 0u) |
                (a1.z > 0.f ? 64u : 0u) | (a1.w > 0.f ? 128u : 0u);

  #pragma unroll
  for (int off = 32; off > 0; off >>= 1) {
    deg += __shfl_down(deg, off);
    dot += __shfl_down(dot, off);
  }
  __shared__ float rd[4], rt[4], rm[4], rz[4];
  if (lane == 0) { rd[wid] = deg; rt[wid] = dot; }
  __syncthreads();
  deg = rd[0] + rd[1] + rd[2] + rd[3];
  dot = rt[0] + rt[1] + rt[2] + rt[3];
  float degc = deg > 0.f ? deg : 1.f;
  float s2p = (dot / degc) * LOG2E;

  float4 p0 = *(const float4*)(t1b + t * 8);
  float4 p1 = *(const float4*)(t1b + t * 8 + 4);
  float al[8];
  al[0] = (mb & 1)   ? alpha_of(p0.x + s2p) : NEG_BIG;
  al[1] = (mb & 2)   ? alpha_of(p0.y + s2p) : NEG_BIG;
  al[2] = (mb & 4)   ? alpha_of(p0.z + s2p) : NEG_BIG;
  al[3] = (mb & 8)   ? alpha_of(p0.w + s2p) : NEG_BIG;
  al[4] = (mb & 16)  ? alpha_of(p1.x + s2p) : NEG_BIG;
  al[5] = (mb & 32)  ? alpha_of(p1.y + s2p) : NEG_BIG;
  al[6] = (mb & 64)  ? alpha_of(p1.z + s2p) : NEG_BIG;
  al[7] = (mb & 128) ? alpha_of(p1.w + s2p) : NEG_BIG;
  float m = NEG_BIG;
  #pragma unroll
  for (int j = 0; j < 8; ++j) m = fmaxf(m, al[j]);
  #pragma unroll
  for (int off = 32; off > 0; off >>= 1) m = fmaxf(m, __shfl_down(m, off));
  if (lane == 0) rm[wid] = m;
  __syncthreads();
  m = fmaxf(fmaxf(rm[0], rm[1]), fmaxf(rm[2], rm[3]));

  float negmL = -m * LOG2E;
  float z = 0.f;
  #pragma unroll
  for (int j = 0; j < 8; ++j) z += __builtin_amdgcn_exp2f(fmaf(al[j], LOG2E, negmL));
  #pragma unroll
  for (int off = 32; off > 0; off >>= 1) z += __shfl_down(z, off);
  if (lane == 0) rz[wid] = z;
  __syncthreads();
  float zf = rz[0] + rz[1] + rz[2] + rz[3];

  float cr, wn;
  if (deg > 0.f) { cr = negmL - log2f(zf); wn = 0.f; }
  else           { cr = 0.f;               wn = 1.0f / (float)N; }
  f16x8 hw;
  #pragma unroll
  for (int j = 0; j < 8; ++j) {
    float w = ((mb >> j) & 1u) ? __builtin_amdgcn_exp2f(fmaf(al[j], LOG2E, cr)) : wn;
    hw[j] = (f16)w;
  }
  *(f16x8*)(Wm + (size_t)row * N + t * 8) = hw;
}

// ---------------- kernel 4: f16 MFMA GEMM, K-split 2, XCD-swizzled ----------
// out[8192,256] = W[8192,2048] @ word[2048,256].
// grid 1024: rt = bid & 255, fg = bid >> 8  ==> the 4 blocks sharing a 32-row
// A-panel have equal bid%8 -> same XCD -> A HBM-fetched once, L2-hit 3x.
// 256 thr = 4 waves: fsub = w&1, ks = w>>1. Wave tile 32x32, K-half 1024.
// R7-proven 2x4 register ping-pong (no spill), single-barrier K reduction.
__global__ __launch_bounds__(256, 4) void k_gemm(const f16* __restrict__ Wm,
                                                 const f16* __restrict__ wordT,
                                                 float* __restrict__ out) {
  __shared__ float red[2][16][64];   // 8KB

  const int t = threadIdx.x;
  const int l = t & 63;
  const int w = t >> 6;
  const int fsub = w & 1;
  const int ks = w >> 1;
  const int rt = blockIdx.x & 255;
  const int fg = blockIdx.x >> 8;
  const int m0 = rt * 32;
  const int b = m0 >> 11;
  const int ft = fg * 2 + fsub;

  // A-frag: lane l -> row m0+(l&31), k = ks*1024 + kc*16 + (l>>5)*8 + j
  const f16* Ap = Wm + (size_t)(m0 + (l & 31)) * N + ks * 1024 + (l >> 5) * 8;
  // B-frag: [ft][kcglob][lane][8], kcglob = ks*64 + kc
  const f16* Bp = wordT + (size_t)b * F * N + ((size_t)(ft * 128 + ks * 64) * 64 + l) * 8;

  f32x16 acc = {0.f,0.f,0.f,0.f,0.f,0.f,0.f,0.f,0.f,0.f,0.f,0.f,0.f,0.f,0.f,0.f};

  f16x8 a0[4], b0[4], a1[4], b1[4];
  #pragma unroll
  for (int c = 0; c < 4; ++c) {
    a0[c] = *(const f16x8*)(Ap + (size_t)c * 16);
    b0[c] = *(const f16x8*)(Bp + (size_t)c * 512);
  }

  for (int kc = 0; kc < 64; kc += 8) {
    #pragma unroll
    for (int c = 0; c < 4; ++c) {
      a1[c] = *(const f16x8*)(Ap + (size_t)(kc + 4 + c) * 16);
      b1[c] = *(const f16x8*)(Bp + (size_t)(kc + 4 + c) * 512);
    }
    #pragma unroll
    for (int c = 0; c < 4; ++c)
      acc = __builtin_amdgcn_mfma_f32_32x32x16_f16(a0[c], b0[c], acc, 0, 0, 0);
    if (kc + 8 < 64) {
      #pragma unroll
      for (int c = 0; c < 4; ++c) {
        a0[c] = *(const f16x8*)(Ap + (size_t)(kc + 8 + c) * 16);
        b0[c] = *(const f16x8*)(Bp + (size_t)(kc + 8 + c) * 512);
      }
    }
    #pragma unroll
    for (int c = 0; c < 4; ++c)
      acc = __builtin_amdgcn_mfma_f32_32x32x16_f16(a1[c], b1[c], acc, 0, 0, 0);
  }

  // cross-wave K reduction
  if (ks == 1) {
    #pragma unroll
    for (int reg = 0; reg < 16; ++reg) red[fsub][reg][l] = acc[reg];
  }
  __syncthreads();
  if (ks == 0) {
    const int fcol = ft * 32 + (l & 31);
    #pragma unroll
    for (int reg = 0; reg < 16; ++reg) {
      float v = acc[reg] + red[fsub][reg][l];
      int row = m0 + (reg & 3) + 8 * (reg >> 2) + 4 * (l >> 5);
      out[(size_t)row * F + fcol] = v;
    }
  }
}

extern "C" void kernel_launch(void* const* d_in, const int* in_sizes, int n_in,
                              void* d_out, int out_size, void* d_ws, size_t ws_size,
                              hipStream_t stream) {
  const float* word = (const float*)d_in[0];
  const float* adj  = (const float*)d_in[1];
  const float* W1   = (const float*)d_in[2];
  const float* W2   = (const float*)d_in[3];
  const float* w3   = (const float*)d_in[4];
  float* out = (float*)d_out;
  float* ws  = (float*)d_ws;
  f16* wordT = (f16*)((char*)d_ws + WT_OFF);
  f16* Wm    = (f16*)((char*)d_ws + W_OFF);

  k_v<<<64, 256, 0, stream>>>(W1, W2, w3, ws);
  k_prep<<<dim3(N / 32, B), 256, 0, stream>>>(word, ws, wordT);
  k_stats<<<B * N, 256, 0, stream>>>(adj, ws, Wm);
  k_gemm<<<1024, 256, 0, stream>>>(Wm, wordT, out);
}

// Round 10
// 140.283 us; speedup vs baseline: 1.2090x; 1.1272x over previous
//
#include <hip/hip_runtime.h>

#define B 4
#define N 2048      // N1 == N2
#define F 256
#define O 256
#define LOG2E 1.4426950408889634f
#define NEG_BIG -9000000000000000.0f

typedef _Float16 f16;
typedef f16 f16x8 __attribute__((ext_vector_type(8)));
typedef float f32x16 __attribute__((ext_vector_type(16)));

// ws float-index layout (small scalars region)
#define WS_V1 0
#define WS_V2 256
#define WS_T1 512              // t1 * LOG2E  per (b,n2)
#define WS_T2 (512 + B*N)     // t2 (unscaled) per (b,n2)
// byte offsets in d_ws
#define WT_OFF (1u << 20)     // wordT swizzled: f16 [B][ft(8)][kc(128)][lane(64)][8] (4 MB)
#define W_OFF  (8u << 20)     // W: f16 [B*N][N] softmax weights row-major (33.5 MB)

__device__ __forceinline__ float alpha_of(float pre2) {
  return __builtin_amdgcn_exp2f(fmaxf(pre2, 0.2f * pre2));
}

// ---------------- kernel 1: v1 = W1 @ w3a, v2 = W2 @ w3b ----------------
__global__ __launch_bounds__(256) void k_v(const float* __restrict__ W1,
                                           const float* __restrict__ W2,
                                           const float* __restrict__ w3,
                                           float* __restrict__ ws) {
  int tid = threadIdx.x;
  int lane = tid & 63;
  int f = blockIdx.x * 4 + (tid >> 6);
  float a = 0.f, b = 0.f;
  #pragma unroll
  for (int k = 0; k < 4; ++k) {
    int o = lane + 64 * k;
    a += W1[f * O + o] * w3[o];
    b += W2[f * O + o] * w3[O + o];
  }
  #pragma unroll
  for (int off = 32; off > 0; off >>= 1) {
    a += __shfl_down(a, off);
    b += __shfl_down(b, off);
  }
  if (lane == 0) {
    ws[WS_V1 + f] = a;
    ws[WS_V2 + f] = b;
  }
}

// ---------------- kernel 2: k_prep = t1/t2 dots + swizzled f16 transpose ----
__global__ __launch_bounds__(256) void k_prep(const float* __restrict__ word,
                                              float* __restrict__ ws,
                                              f16* __restrict__ wordT) {
  __shared__ float v1s[F], v2s[F];
  __shared__ __align__(16) f16 tile[F][40];   // [f][r]
  int t = threadIdx.x;
  int k0 = blockIdx.x * 32;
  int b = blockIdx.y;

  if (t < 64)       ((float4*)v1s)[t]      = ((const float4*)(ws + WS_V1))[t];
  else if (t < 128) ((float4*)v2s)[t - 64] = ((const float4*)(ws + WS_V2))[t - 64];
  __syncthreads();

  int r = t >> 3;        // 0..31
  int cg = t & 7;
  const float* wrow = word + ((size_t)(b * N + k0 + r)) * F;
  float a = 0.f, bb = 0.f;
  #pragma unroll
  for (int i = 0; i < 8; ++i) {
    int c = i * 32 + cg * 4;
    float4 w = *(const float4*)(wrow + c);
    float4 x1 = *(const float4*)(v1s + c);
    float4 x2 = *(const float4*)(v2s + c);
    a  += w.x * x1.x + w.y * x1.y + w.z * x1.z + w.w * x1.w;
    bb += w.x * x2.x + w.y * x2.y + w.z * x2.z + w.w * x2.w;
    tile[c + 0][r] = (f16)w.x;
    tile[c + 1][r] = (f16)w.y;
    tile[c + 2][r] = (f16)w.z;
    tile[c + 3][r] = (f16)w.w;
  }
  #pragma unroll
  for (int off = 4; off > 0; off >>= 1) {
    a  += __shfl_down(a, off);
    bb += __shfl_down(bb, off);
  }
  if (cg == 0) {
    ws[WS_T1 + b * N + k0 + r] = a * LOG2E;
    ws[WS_T2 + b * N + k0 + r] = bb;
  }
  __syncthreads();

  // swizzled writes: [ft][kc][lane][8]; B-frag: f = ft*32+(l&31), k = kc*16+(l>>5)*8+j
  size_t base = (size_t)b * F * N;
  #pragma unroll
  for (int i = 0; i < 4; ++i) {
    int idx = t + 256 * i;
    int ft = idx >> 7, c = (idx >> 6) & 1, l = idx & 63;
    int f = ft * 32 + (l & 31);
    int rr = c * 16 + ((l >> 5) * 8);
    f16x8 h = *(const f16x8*)&tile[f][rr];
    *(f16x8*)(wordT + base + ((size_t)((ft * 128 + (k0 >> 4) + c) * 64 + l)) * 8) = h;
  }
}

// -------- kernel 3: per-row stats + fused softmax-weight write (f16) --------
__global__ __launch_bounds__(256) void k_stats(const float* __restrict__ adj,
                                               float* __restrict__ ws,
                                               f16* __restrict__ Wm) {
  int row = blockIdx.x;
  int b = row >> 11;
  int t = threadIdx.x;
  int wid = t >> 6, lane = t & 63;
  const float* arow = adj + (size_t)row * N;
  const float* t1b = ws + WS_T1 + b * N;
  const float* t2b = ws + WS_T2 + b * N;

  float4 a0 = *(const float4*)(arow + t * 8);
  float4 a1 = *(const float4*)(arow + t * 8 + 4);
  float4 u0 = *(const float4*)(t2b + t * 8);
  float4 u1 = *(const float4*)(t2b + t * 8 + 4);
  float deg = a0.x + a0.y + a0.z + a0.w + a1.x + a1.y + a1.z + a1.w;
  float dot = a0.x * u0.x + a0.y * u0.y + a0.z * u0.z + a0.w * u0.w +
              a1.x * u1.x + a1.y * u1.y + a1.z * u1.z + a1.w * u1.w;
  unsigned mb = (a0.x > 0.f ? 1u : 0u) | (a0.y > 0.f ? 2u : 0u) |
                (a0.z > 0.f ? 4u : 0u) | (a0.w > 0.f ? 8u : 0u) |
                (a1.x > 0.f ? 16u : 0u) | (a1.y > 0.f ? 32u : 0u) |
                (a1.z > 0.f ? 64u : 0u) | (a1.w > 0.f ? 128u : 0u);

  #pragma unroll
  for (int off = 32; off > 0; off >>= 1) {
    deg += __shfl_down(deg, off);
    dot += __shfl_down(dot, off);
  }
  __shared__ float rd[4], rt[4], rm[4], rz[4];
  if (lane == 0) { rd[wid] = deg; rt[wid] = dot; }
  __syncthreads();
  deg = rd[0] + rd[1] + rd[2] + rd[3];
  dot = rt[0] + rt[1] + rt[2] + rt[3];
  float degc = deg > 0.f ? deg : 1.f;
  float s2p = (dot / degc) * LOG2E;

  float4 p0 = *(const float4*)(t1b + t * 8);
  float4 p1 = *(const float4*)(t1b + t * 8 + 4);
  float al[8];
  al[0] = (mb & 1)   ? alpha_of(p0.x + s2p) : NEG_BIG;
  al[1] = (mb & 2)   ? alpha_of(p0.y + s2p) : NEG_BIG;
  al[2] = (mb & 4)   ? alpha_of(p0.z + s2p) : NEG_BIG;
  al[3] = (mb & 8)   ? alpha_of(p0.w + s2p) : NEG_BIG;
  al[4] = (mb & 16)  ? alpha_of(p1.x + s2p) : NEG_BIG;
  al[5] = (mb & 32)  ? alpha_of(p1.y + s2p) : NEG_BIG;
  al[6] = (mb & 64)  ? alpha_of(p1.z + s2p) : NEG_BIG;
  al[7] = (mb & 128) ? alpha_of(p1.w + s2p) : NEG_BIG;
  float m = NEG_BIG;
  #pragma unroll
  for (int j = 0; j < 8; ++j) m = fmaxf(m, al[j]);
  #pragma unroll
  for (int off = 32; off > 0; off >>= 1) m = fmaxf(m, __shfl_down(m, off));
  if (lane == 0) rm[wid] = m;
  __syncthreads();
  m = fmaxf(fmaxf(rm[0], rm[1]), fmaxf(rm[2], rm[3]));

  float negmL = -m * LOG2E;
  float z = 0.f;
  #pragma unroll
  for (int j = 0; j < 8; ++j) z += __builtin_amdgcn_exp2f(fmaf(al[j], LOG2E, negmL));
  #pragma unroll
  for (int off = 32; off > 0; off >>= 1) z += __shfl_down(z, off);
  if (lane == 0) rz[wid] = z;
  __syncthreads();
  float zf = rz[0] + rz[1] + rz[2] + rz[3];

  float cr, wn;
  if (deg > 0.f) { cr = negmL - log2f(zf); wn = 0.f; }
  else           { cr = 0.f;               wn = 1.0f / (float)N; }
  f16x8 hw;
  #pragma unroll
  for (int j = 0; j < 8; ++j) {
    float w = ((mb >> j) & 1u) ? __builtin_amdgcn_exp2f(fmaf(al[j], LOG2E, cr)) : wn;
    hw[j] = (f16)w;
  }
  *(f16x8*)(Wm + (size_t)row * N + t * 8) = hw;
}

// ---------------- kernel 4: LDS-staged f16 MFMA GEMM -----------------------
// out[8192,256] = W[8192,2048] @ word[2048,256].
// grid 256 (bid = fg*64 + rt -> same-A blocks 64 apart = same XCD), 512 thr
// = 8 waves: ksw = w>>2 (K half), rh2 = (w>>1)&1 (64-row half), ftL = w&1.
// Block tile 128 rows x 64 cols; wave tile 64x32, K-half 1024, acc 32 regs.
// BK=64 double-buffered LDS: A frag-ordered (conflict-free reads), B identity
// (wordT already frag-ordered). One barrier/iter; k-split reduced via LDS.
__global__ __launch_bounds__(512, 1) void k_gemm(const f16* __restrict__ Wm,
                                                 const f16* __restrict__ wordT,
                                                 float* __restrict__ out) {
  // As per buf: [kw2][rhh4][kc4][lane64][8] = 16384 halfs (32 KB)
  // Bs per buf: [kw2][ftL2][kc4][lane64][8] =  8192 halfs (16 KB)
  __shared__ __align__(16) f16 As[2][16384];   // 64 KB
  __shared__ __align__(16) f16 Bs[2][8192];    // 32 KB

  const int t = threadIdx.x;
  const int l = t & 63;
  const int w = t >> 6;
  const int ksw = w >> 2;
  const int rh2 = (w >> 1) & 1;
  const int ftL = w & 1;
  const int rt = blockIdx.x & 63;
  const int fg = blockIdx.x >> 6;
  const int m0 = rt * 128;
  const int b = m0 >> 11;
  const int f0 = fg * 64;

  // ---- staging indices (per thread) ----
  const int srow = t >> 2, sseg = t & 3;            // A: row 0..127, 16-half seg
  const int srhh = srow >> 5, srr = srow & 31;
  const f16* a_src = Wm + (size_t)(m0 + srow) * N + sseg * 16;  // +kw*1024 +it*64
  const int a_dst = ((srhh * 4 + sseg) * 64 + srr) * 8;         // kw0, sub0 slot
  // kw stride in As: 4*4*512 = 8192 halfs; sub stride: 32*8 = 256

  const int sftL = (t >> 8) & 1, skc = (t >> 6) & 3, sln = t & 63;
  const f16* b_src = wordT +
      (((size_t)(b * 8 + fg * 2 + sftL) * 128 + skc) * 64 + sln) * 8;  // +(kw*64+it*4)*512
  const int b_dst = ((sftL * 4 + skc) * 64 + sln) * 8;   // kw stride: 4096 halfs

  f32x16 acc0 = {0.f,0.f,0.f,0.f,0.f,0.f,0.f,0.f,0.f,0.f,0.f,0.f,0.f,0.f,0.f,0.f};
  f32x16 acc1 = {0.f,0.f,0.f,0.f,0.f,0.f,0.f,0.f,0.f,0.f,0.f,0.f,0.f,0.f,0.f,0.f};

  // ---- prologue: stage iter 0 into buf 0 ----
  {
    f16x8 va0 = *(const f16x8*)(a_src);
    f16x8 va1 = *(const f16x8*)(a_src + 8);
    f16x8 va2 = *(const f16x8*)(a_src + 1024);
    f16x8 va3 = *(const f16x8*)(a_src + 1024 + 8);
    f16x8 vb0 = *(const f16x8*)(b_src);
    f16x8 vb1 = *(const f16x8*)(b_src + 64 * 512);
    *(f16x8*)(&As[0][a_dst])              = va0;
    *(f16x8*)(&As[0][a_dst + 256])        = va1;
    *(f16x8*)(&As[0][a_dst + 8192])       = va2;
    *(f16x8*)(&As[0][a_dst + 8192 + 256]) = va3;
    *(f16x8*)(&Bs[0][b_dst])              = vb0;
    *(f16x8*)(&Bs[0][b_dst + 4096])       = vb1;
  }

  // frag base offsets for this wave
  const int afr0 = ((ksw * 4 + rh2 * 2 + 0) * 4) * 512 + l * 8;
  const int afr1 = ((ksw * 4 + rh2 * 2 + 1) * 4) * 512 + l * 8;
  const int bfr0 = ((ksw * 2 + ftL) * 4) * 512 + l * 8;

  for (int it = 0; it < 16; ++it) {
    const int cb = it & 1;
    __syncthreads();

    // issue next-iter global loads (in flight across compute)
    f16x8 va0, va1, va2, va3, vb0, vb1;
    if (it < 15) {
      const f16* as = a_src + (it + 1) * 64;
      const f16* bs = b_src + (size_t)(it + 1) * 4 * 512;
      va0 = *(const f16x8*)(as);
      va1 = *(const f16x8*)(as + 8);
      va2 = *(const f16x8*)(as + 1024);
      va3 = *(const f16x8*)(as + 1024 + 8);
      vb0 = *(const f16x8*)(bs);
      vb1 = *(const f16x8*)(bs + 64 * 512);
    }

    // compute on buf cb
    #pragma unroll
    for (int kc = 0; kc < 4; ++kc) {
      const f16x8 af0 = *(const f16x8*)(&As[cb][afr0 + kc * 512]);
      const f16x8 af1 = *(const f16x8*)(&As[cb][afr1 + kc * 512]);
      const f16x8 bf  = *(const f16x8*)(&Bs[cb][bfr0 + kc * 512]);
      acc0 = __builtin_amdgcn_mfma_f32_32x32x16_f16(af0, bf, acc0, 0, 0, 0);
      acc1 = __builtin_amdgcn_mfma_f32_32x32x16_f16(af1, bf, acc1, 0, 0, 0);
    }

    // write staged data into the other buffer
    if (it < 15) {
      const int nb = cb ^ 1;
      *(f16x8*)(&As[nb][a_dst])              = va0;
      *(f16x8*)(&As[nb][a_dst + 256])        = va1;
      *(f16x8*)(&As[nb][a_dst + 8192])       = va2;
      *(f16x8*)(&As[nb][a_dst + 8192 + 256]) = va3;
      *(f16x8*)(&Bs[nb][b_dst])              = vb0;
      *(f16x8*)(&Bs[nb][b_dst + 4096])       = vb1;
    }
  }

  // ---- k-split reduction via LDS (reuse As[0]: 32 KB; last iter read buf1) ----
  float* red = (float*)&As[0][0];   // [pid8? -> pid4][a2(2)][reg16][lane64]
  const int pid = w & 3;
  if (ksw == 1) {
    #pragma unroll
    for (int reg = 0; reg < 16; ++reg) {
      red[((pid * 2 + 0) * 16 + reg) * 64 + l] = acc0[reg];
      red[((pid * 2 + 1) * 16 + reg) * 64 + l] = acc1[reg];
    }
  }
  __syncthreads();
  if (ksw == 0) {
    const int gcol = f0 + ftL * 32 + (l & 31);
    #pragma unroll
    for (int reg = 0; reg < 16; ++reg) {
      const int lr = (reg & 3) + 8 * (reg >> 2) + 4 * (l >> 5);
      float v0 = acc0[reg] + red[((pid * 2 + 0) * 16 + reg) * 64 + l];
      float v1 = acc1[reg] + red[((pid * 2 + 1) * 16 + reg) * 64 + l];
      out[(size_t)(m0 + rh2 * 64 + 0 * 32 + lr) * F + gcol] = v0;
      out[(size_t)(m0 + rh2 * 64 + 1 * 32 + lr) * F + gcol] = v1;
    }
  }
}

extern "C" void kernel_launch(void* const* d_in, const int* in_sizes, int n_in,
                              void* d_out, int out_size, void* d_ws, size_t ws_size,
                              hipStream_t stream) {
  const float* word = (const float*)d_in[0];
  const float* adj  = (const float*)d_in[1];
  const float* W1   = (const float*)d_in[2];
  const float* W2   = (const float*)d_in[3];
  const float* w3   = (const float*)d_in[4];
  float* out = (float*)d_out;
  float* ws  = (float*)d_ws;
  f16* wordT = (f16*)((char*)d_ws + WT_OFF);
  f16* Wm    = (f16*)((char*)d_ws + W_OFF);

  k_v<<<64, 256, 0, stream>>>(W1, W2, w3, ws);
  k_prep<<<dim3(N / 32, B), 256, 0, stream>>>(word, ws, wordT);
  k_stats<<<B * N, 256, 0, stream>>>(adj, ws, Wm);
  k_gemm<<<256, 512, 0, stream>>>(Wm, wordT, out);
}